// Round 17
// baseline (285.777 us; speedup 1.0000x reference)
//
#include <hip/hip_runtime.h>

#define NB   2
#define NHD  8
#define BH   16
#define HD   16
#define N0   9216
#define N1   2304
#define N2   576
#define W0_  96
#define W1_  48
#define W2_  24
#define M_TOT 18432
#define TEMP 0.25f

// ---------------- projection GEMM (64-row tile): dst[(b,h,n,d)] = sum_c A[m][c]*W[o][c] ----------------
__global__ __launch_bounds__(256) void k_proj(const float* __restrict__ x, const float* __restrict__ tg,
    const float* __restrict__ Wq, const float* __restrict__ Wk, const float* __restrict__ Wv,
    float* __restrict__ q0, float* __restrict__ k0, float* __restrict__ v0)
{
    __shared__ __align__(16) float At[16][68];   // [k][row]
    __shared__ __align__(16) float Wt[16][132];  // [k][o]
    const int t = threadIdx.x;
    const int which = blockIdx.y;
    const float* A  = (which==0)? x : tg;
    const float* Wm = (which==0)? Wq : (which==1? Wk : Wv);
    float* dst      = (which==0)? q0 : (which==1? k0 : v0);
    const int m0 = blockIdx.x * 64;
    const int tx = t & 15, ty = t >> 4;

    float acc[4][8];
#pragma unroll
    for(int i=0;i<4;i++)
#pragma unroll
        for(int j=0;j<8;j++) acc[i][j]=0.f;

    const int ar = t>>2, akq = (t&3)*4;
    const int wo = t>>1, wkq = (t&1)*8;

    for(int kc=0;kc<128;kc+=16){
        float4 av = *(const float4*)(A + (m0+ar)*128 + kc + akq);
        At[akq+0][ar] = av.x;
        At[akq+1][ar] = av.y;
        At[akq+2][ar] = av.z;
        At[akq+3][ar] = av.w;
        float4 w0 = *(const float4*)(Wm + wo*128 + kc + wkq);
        float4 w1 = *(const float4*)(Wm + wo*128 + kc + wkq + 4);
        Wt[wkq+0][wo] = w0.x; Wt[wkq+1][wo] = w0.y;
        Wt[wkq+2][wo] = w0.z; Wt[wkq+3][wo] = w0.w;
        Wt[wkq+4][wo] = w1.x; Wt[wkq+5][wo] = w1.y;
        Wt[wkq+6][wo] = w1.z; Wt[wkq+7][wo] = w1.w;
        __syncthreads();
#pragma unroll
        for(int kk=0;kk<16;kk++){
            float4 a4 = *(const float4*)&At[kk][ty*4];
            float4 wa = *(const float4*)&Wt[kk][tx*4];
            float4 wb = *(const float4*)&Wt[kk][64 + tx*4];
            float avr[4] = {a4.x,a4.y,a4.z,a4.w};
            float wvr[8] = {wa.x,wa.y,wa.z,wa.w, wb.x,wb.y,wb.z,wb.w};
#pragma unroll
            for(int i=0;i<4;i++)
#pragma unroll
                for(int j=0;j<8;j++) acc[i][j] += avr[i]*wvr[j];
        }
        __syncthreads();
    }
    const int hA = tx>>2, dA = (tx&3)*4;
#pragma unroll
    for(int i=0;i<4;i++){
        int m = m0 + ty*4 + i;
        int b = m / N0; int n = m - b*N0;
        float4 sA = make_float4(acc[i][0], acc[i][1], acc[i][2], acc[i][3]);
        float4 sB = make_float4(acc[i][4], acc[i][5], acc[i][6], acc[i][7]);
        *(float4*)(dst + ((b*NHD + hA    )*N0 + n)*16 + dA) = sA;
        *(float4*)(dst + ((b*NHD + hA + 4)*N0 + n)*16 + dA) = sB;
    }
}

// ---- FUSED pooling: level0 -> level1 (row layout) AND level1 -> level2 (q row, k/v transposed) ----
__global__ __launch_bounds__(256) void k_pool01(const float4* __restrict__ src0,
    float4* __restrict__ dst1, float4* __restrict__ q2f,
    float4* __restrict__ k2T, float4* __restrict__ v2T)
{
    int tid = blockIdx.x*256 + threadIdx.x;
    if (tid >= 110592) return;
    int d4 = tid & 3;
    int rest = tid >> 2;
    int n2 = rest % N2; int g = rest / N2;     // g in [0,48): 0-15 q, 16-31 k, 32-47 v
    int yo2 = n2 / W2_, xo2 = n2 - yo2*W2_;

    const float4* s = src0 + g*N0*4;
    float4* d1 = dst1 + g*N1*4;
    float4 l1[4];
#pragma unroll
    for(int yy=0;yy<2;yy++){
#pragma unroll
        for(int xx=0;xx<2;xx++){
            int y1 = 2*yo2+yy, x1 = 2*xo2+xx;
            int n1 = y1*W1_ + x1;
            int cbase = (2*y1)*W0_ + 2*x1;
            float4 a = s[(cbase       )*4 + d4];
            float4 b = s[(cbase+1     )*4 + d4];
            float4 c = s[(cbase+W0_   )*4 + d4];
            float4 d = s[(cbase+W0_+1 )*4 + d4];
            float4 o;
            o.x = 0.25f*(a.x+b.x+c.x+d.x);
            o.y = 0.25f*(a.y+b.y+c.y+d.y);
            o.z = 0.25f*(a.z+b.z+c.z+d.z);
            o.w = 0.25f*(a.w+b.w+c.w+d.w);
            d1[n1*4 + d4] = o;
            l1[yy*2+xx] = o;
        }
    }
    float4 o2;
    o2.x = 0.25f*(l1[0].x+l1[1].x+l1[2].x+l1[3].x);
    o2.y = 0.25f*(l1[0].y+l1[1].y+l1[2].y+l1[3].y);
    o2.z = 0.25f*(l1[0].z+l1[1].z+l1[2].z+l1[3].z);
    o2.w = 0.25f*(l1[0].w+l1[1].w+l1[2].w+l1[3].w);
    int grp = g >> 4, bh = g & 15;
    if (grp == 0)      q2f[(bh*N2 + n2)*4 + d4] = o2;
    else if (grp == 1) k2T[(bh*4 + d4)*N2 + n2] = o2;
    else               v2T[(bh*4 + d4)*N2 + n2] = o2;
}

// ---- level-2 attention + top-16: 2 queries/wave, coalesced transposed k/v, 128-VGPR budget ----
__global__ __launch_bounds__(256, 4) void k_attn2(const float* __restrict__ q2, const float* __restrict__ k2,
    const float* __restrict__ v2, float* __restrict__ msg2, int* __restrict__ idx2)
{
    const int bh = blockIdx.x;
    const int wv = threadIdx.x>>6, lane = threadIdx.x&63;
    const int qbase = blockIdx.y*8 + wv*2;   // queries qbase, qbase+1

    float qa[16], qb[16];
    const float4* qp = (const float4*)(q2 + (bh*N2 + qbase)*16);
#pragma unroll
    for(int dq=0;dq<4;dq++){
        float4 va = qp[dq];
        qa[dq*4+0]=va.x; qa[dq*4+1]=va.y; qa[dq*4+2]=va.z; qa[dq*4+3]=va.w;
        float4 vb = qp[4+dq];
        qb[dq*4+0]=vb.x; qb[dq*4+1]=vb.y; qb[dq*4+2]=vb.z; qb[dq*4+3]=vb.w;
    }

    const float4* kT = (const float4*)k2 + bh*4*N2;   // [dg][m]
    const float4* vT = (const float4*)v2 + bh*4*N2;

    // pass 1: scores + running max (per-query op order identical to 1q version)
    float eva[9], evb[9];
    float mxa = -1e30f, mxb = -1e30f;
#pragma unroll
    for(int t9=0;t9<9;t9++){
        int m = t9*64 + lane;
        float sa = 0.f, sb = 0.f;
#pragma unroll
        for(int dg=0;dg<4;dg++){
            float4 kv = kT[dg*N2 + m];      // coalesced; shared by both queries
            sa += qa[dg*4+0]*kv.x; sa += qa[dg*4+1]*kv.y;
            sa += qa[dg*4+2]*kv.z; sa += qa[dg*4+3]*kv.w;
            sb += qb[dg*4+0]*kv.x; sb += qb[dg*4+1]*kv.y;
            sb += qb[dg*4+2]*kv.z; sb += qb[dg*4+3]*kv.w;
        }
        sa *= TEMP; sb *= TEMP;
        eva[t9]=sa; evb[t9]=sb;
        mxa = fmaxf(mxa, sa); mxb = fmaxf(mxb, sb);
    }
#pragma unroll
    for(int st=1; st<64; st<<=1){
        mxa = fmaxf(mxa, __shfl_xor(mxa, st));
        mxb = fmaxf(mxb, __shfl_xor(mxb, st));
    }

    // pass 2: exp, sum, P·V (v rows shared)
    float suma=0.f, sumb=0.f;
    float acca[16], accb[16];
#pragma unroll
    for(int d=0;d<16;d++){ acca[d]=0.f; accb[d]=0.f; }
#pragma unroll
    for(int t9=0;t9<9;t9++){
        int m = t9*64 + lane;
        float ea = expf(eva[t9]-mxa);
        float eb = expf(evb[t9]-mxb);
        eva[t9]=ea; evb[t9]=eb;
        suma += ea; sumb += eb;
#pragma unroll
        for(int dg=0;dg<4;dg++){
            float4 vv = vT[dg*N2 + m];
            acca[dg*4+0] += ea*vv.x; acca[dg*4+1] += ea*vv.y;
            acca[dg*4+2] += ea*vv.z; acca[dg*4+3] += ea*vv.w;
            accb[dg*4+0] += eb*vv.x; accb[dg*4+1] += eb*vv.y;
            accb[dg*4+2] += eb*vv.z; accb[dg*4+3] += eb*vv.w;
        }
    }
#pragma unroll
    for(int st=1; st<64; st<<=1){
        suma += __shfl_xor(suma, st);
        sumb += __shfl_xor(sumb, st);
    }

    // dim-splitting butterfly reductions (independent chains)
    const bool b5 = (lane & 32) != 0;
    float r8a[8], r8b[8];
#pragma unroll
    for(int i=0;i<8;i++){
        float sna  = b5 ? acca[i]   : acca[i+8];
        float kpa  = b5 ? acca[i+8] : acca[i];
        r8a[i] = kpa + __shfl_xor(sna, 32);
        float snb  = b5 ? accb[i]   : accb[i+8];
        float kpb  = b5 ? accb[i+8] : accb[i];
        r8b[i] = kpb + __shfl_xor(snb, 32);
    }
    const bool b4 = (lane & 16) != 0;
    float r4a[4], r4b[4];
#pragma unroll
    for(int i=0;i<4;i++){
        float sna  = b4 ? r8a[i]   : r8a[i+4];
        float kpa  = b4 ? r8a[i+4] : r8a[i];
        r4a[i] = kpa + __shfl_xor(sna, 16);
        float snb  = b4 ? r8b[i]   : r8b[i+4];
        float kpb  = b4 ? r8b[i+4] : r8b[i];
        r4b[i] = kpb + __shfl_xor(snb, 16);
    }
    const bool b3 = (lane & 8) != 0;
    float r2a[2], r2b[2];
#pragma unroll
    for(int i=0;i<2;i++){
        float sna  = b3 ? r4a[i]   : r4a[i+2];
        float kpa  = b3 ? r4a[i+2] : r4a[i];
        r2a[i] = kpa + __shfl_xor(sna, 8);
        float snb  = b3 ? r4b[i]   : r4b[i+2];
        float kpb  = b3 ? r4b[i+2] : r4b[i];
        r2b[i] = kpb + __shfl_xor(snb, 8);
    }
    const bool b2 = (lane & 4) != 0;
    {
        float sna  = b2 ? r2a[0] : r2a[1];
        float kpa  = b2 ? r2a[1] : r2a[0];
        r2a[0] = kpa + __shfl_xor(sna, 4);
        float snb  = b2 ? r2b[0] : r2b[1];
        float kpb  = b2 ? r2b[1] : r2b[0];
        r2b[0] = kpb + __shfl_xor(snb, 4);
    }
    r2a[0] += __shfl_xor(r2a[0], 2);  r2b[0] += __shfl_xor(r2b[0], 2);
    r2a[0] += __shfl_xor(r2a[0], 1);  r2b[0] += __shfl_xor(r2b[0], 1);

    float inva = 1.0f/suma, invb = 1.0f/sumb;
    if ((lane&3)==0){
        int d = lane>>2;
        msg2[(bh*N2+qbase  )*16 + d] = r2a[0]*inva;
        msg2[(bh*N2+qbase+1)*16 + d] = r2b[0]*invb;
    }

    // ---- top-16 for query A: presort 9 values desc (val, idx asc), pop heads ----
    {
        int id[9];
#pragma unroll
        for(int i=0;i<9;i++) id[i]=i;
#pragma unroll
        for(int p=0;p<8;p++){
#pragma unroll
            for(int i=0;i<8-p;i++){
                bool sw = (eva[i+1] > eva[i]) || (eva[i+1]==eva[i] && id[i+1]<id[i]);
                float tv = sw? eva[i+1]:eva[i]; float bv2 = sw? eva[i]:eva[i+1];
                int   ti = sw? id[i+1]:id[i]; int   bi  = sw? id[i]:id[i+1];
                eva[i]=tv; eva[i+1]=bv2; id[i]=ti; id[i+1]=bi;
            }
        }
        int* ip = idx2 + (bh*N2+qbase)*16;
        for(int it=0; it<16; it++){
            float bv = eva[0];
            int   bm = id[0]*64 + lane;
#pragma unroll
            for(int st=1; st<64; st<<=1){
                float ov = __shfl_xor(bv, st);
                int   om = __shfl_xor(bm, st);
                if (ov > bv || (ov==bv && om < bm)){ bv=ov; bm=om; }
            }
            if (lane==0) ip[it] = bm;
            if ((bm & 63) == lane){
#pragma unroll
                for(int i=0;i<8;i++){ eva[i]=eva[i+1]; id[i]=id[i+1]; }
                eva[8] = -1e30f;
            }
        }
    }
    // ---- top-16 for query B ----
    {
        int id[9];
#pragma unroll
        for(int i=0;i<9;i++) id[i]=i;
#pragma unroll
        for(int p=0;p<8;p++){
#pragma unroll
            for(int i=0;i<8-p;i++){
                bool sw = (evb[i+1] > evb[i]) || (evb[i+1]==evb[i] && id[i+1]<id[i]);
                float tv = sw? evb[i+1]:evb[i]; float bv2 = sw? evb[i]:evb[i+1];
                int   ti = sw? id[i+1]:id[i]; int   bi  = sw? id[i]:id[i+1];
                evb[i]=tv; evb[i+1]=bv2; id[i]=ti; id[i+1]=bi;
            }
        }
        int* ip = idx2 + (bh*N2+qbase+1)*16;
        for(int it=0; it<16; it++){
            float bv = evb[0];
            int   bm = id[0]*64 + lane;
#pragma unroll
            for(int st=1; st<64; st<<=1){
                float ov = __shfl_xor(bv, st);
                int   om = __shfl_xor(bm, st);
                if (ov > bv || (ov==bv && om < bm)){ bv=ov; bm=om; }
            }
            if (lane==0) ip[it] = bm;
            if ((bm & 63) == lane){
#pragma unroll
                for(int i=0;i<8;i++){ evb[i]=evb[i+1]; id[i]=id[i+1]; }
                evb[8] = -1e30f;
            }
        }
    }
}

// ---- FUSED refinement: wave owns 1 parent + its 4 children; shared candidate set, no barrier ----
__global__ __launch_bounds__(256) void k_ref10(
    const float* __restrict__ q1, const float* __restrict__ k1, const float* __restrict__ v1,
    const float* __restrict__ q0, const float* __restrict__ k0, const float* __restrict__ v0,
    const float* __restrict__ msg2, const int* __restrict__ idx2, float* __restrict__ msg0)
{
    __shared__ float msg1s[4][16];
    __shared__ int   idx1s[4][8];
    // XCD swizzle: 9216 blocks = 8 x 1152; each XCD owns 2 contiguous bh
    const int bid = (blockIdx.x & 7)*1152 + (blockIdx.x >> 3);
    const int bh = bid / 576, tile = bid - bh*576;
    const int tyy = tile / 24, txx = tile - tyy*24;
    const int py0 = tyy*2, px0 = txx*2;      // 2x2 parent tile origin (level-1 coords)
    const int wv = threadIdx.x>>6, lane = threadIdx.x&63;

    const int ppy = py0 + (wv>>1), ppx = px0 + (wv&1);   // this wave's parent (level-1)

    // ---------- phase 1: ref1 for parent wv ----------
    {
        const int n  = ppy*W1_ + ppx;
        const int par = (ppy>>1)*W2_ + (ppx>>1);
        const int kk = lane>>2, tt = lane&3, dy = tt>>1, dx = tt&1;
        int p = idx2[(bh*N2+par)*16 + kk];
        int ky = p / W2_, kx = p - ky*W2_;
        int child = (2*ky+dy)*W1_ + 2*kx+dx;

        const float* qp = q1 + (bh*N1+n)*16;
        float qr[16];
#pragma unroll
        for(int d=0; d<16; d+=4){
            float4 qq = *(const float4*)(qp+d);
            qr[d]=qq.x; qr[d+1]=qq.y; qr[d+2]=qq.z; qr[d+3]=qq.w;
        }
        const float4* kp = (const float4*)(k1 + (bh*N1+child)*16);
        float s = 0.f;
#pragma unroll
        for(int dq=0;dq<4;dq++){
            float4 kv = kp[dq];
            s += qr[dq*4+0]*kv.x + qr[dq*4+1]*kv.y + qr[dq*4+2]*kv.z + qr[dq*4+3]*kv.w;
        }
        s *= TEMP;
        float e = expf(s);
        float sum = e;
#pragma unroll
        for(int st=1; st<64; st<<=1) sum += __shfl_xor(sum, st);

        float acc[16];
        const float4* vp = (const float4*)(v1 + (bh*N1+child)*16);
#pragma unroll
        for(int dq=0;dq<4;dq++){
            float4 vv = vp[dq];
            acc[dq*4+0]=e*vv.x; acc[dq*4+1]=e*vv.y; acc[dq*4+2]=e*vv.z; acc[dq*4+3]=e*vv.w;
        }
        const bool b5 = (lane & 32) != 0;
        float r8[8];
#pragma unroll
        for(int ii=0;ii<8;ii++){
            float snd  = b5 ? acc[ii]   : acc[ii+8];
            float kept = b5 ? acc[ii+8] : acc[ii];
            r8[ii] = kept + __shfl_xor(snd, 32);
        }
        const bool b4 = (lane & 16) != 0;
        float r4[4];
#pragma unroll
        for(int ii=0;ii<4;ii++){
            float snd  = b4 ? r8[ii]   : r8[ii+4];
            float kept = b4 ? r8[ii+4] : r8[ii];
            r4[ii] = kept + __shfl_xor(snd, 16);
        }
        const bool b3 = (lane & 8) != 0;
        float r2[2];
#pragma unroll
        for(int ii=0;ii<2;ii++){
            float snd  = b3 ? r4[ii]   : r4[ii+2];
            float kept = b3 ? r4[ii+2] : r4[ii];
            r2[ii] = kept + __shfl_xor(snd, 8);
        }
        const bool b2 = (lane & 4) != 0;
        {
            float snd  = b2 ? r2[0] : r2[1];
            float kept = b2 ? r2[1] : r2[0];
            r2[0] = kept + __shfl_xor(snd, 4);
        }
        r2[0] += __shfl_xor(r2[0], 2);
        r2[0] += __shfl_xor(r2[0], 1);

        float inv1 = 1.0f/sum;
        if ((lane&3)==0){
            int d = lane>>2;
            msg1s[wv][d] = msg2[(bh*N2+par)*16 + d] + r2[0]*inv1;
        }
        int cnt = 0;
#pragma unroll
        for(int ii=0;ii<64;ii++){
            float si = __shfl(s, ii);
            if (si > s || (si == s && ii < lane)) cnt++;
        }
        if (cnt < 8) idx1s[wv][cnt] = child;
    }
    // no __syncthreads: each wave reads only its own msg1s[wv]/idx1s[wv] (in-wave DS order)

    // ---------- phase 2: this parent's 4 children; candidate set shared across both iterations ----------
    const int j = lane & 31, sub = lane >> 5;
    const int kk = j>>2, tt = j&3, dy = tt>>1, dx = tt&1;
    int p = idx1s[wv][kk];
    int ky = p / W1_, kx = p - ky*W1_;
    int child = (2*ky+dy)*W0_ + 2*kx+dx;

    float kr[16];
    {
        const float4* kp = (const float4*)(k0 + (bh*N0+child)*16);
#pragma unroll
        for(int dq=0;dq<4;dq++){
            float4 kv = kp[dq];
            kr[dq*4+0]=kv.x; kr[dq*4+1]=kv.y; kr[dq*4+2]=kv.z; kr[dq*4+3]=kv.w;
        }
    }
    const int cy0 = 2*ppy, cx0 = 2*ppx + sub;
    int nq[2];
    float s_[2];
#pragma unroll
    for(int it=0; it<2; it++){
        nq[it] = (cy0+it)*W0_ + cx0;
        const float* qp = q0 + (bh*N0+nq[it])*16;
        float qr[16];
#pragma unroll
        for(int d=0; d<16; d+=4){
            float4 qq = *(const float4*)(qp+d);
            qr[d]=qq.x; qr[d+1]=qq.y; qr[d+2]=qq.z; qr[d+3]=qq.w;
        }
        float s = 0.f;
#pragma unroll
        for(int dq=0;dq<4;dq++){
            s += qr[dq*4+0]*kr[dq*4+0] + qr[dq*4+1]*kr[dq*4+1]
               + qr[dq*4+2]*kr[dq*4+2] + qr[dq*4+3]*kr[dq*4+3];
        }
        s_[it] = s * TEMP;
    }
    float vr[16];
    {
        const float4* vp = (const float4*)(v0 + (bh*N0+child)*16);
#pragma unroll
        for(int dq=0;dq<4;dq++){
            float4 vv = vp[dq];
            vr[dq*4+0]=vv.x; vr[dq*4+1]=vv.y; vr[dq*4+2]=vv.z; vr[dq*4+3]=vv.w;
        }
    }
    const float m1d = msg1s[wv][j>>1];

#pragma unroll
    for(int it=0; it<2; it++){
        float e = expf(s_[it]);
        float sum = e;
#pragma unroll
        for(int st=1; st<32; st<<=1) sum += __shfl_xor(sum, st);

        float acc[16];
#pragma unroll
        for(int d=0;d<16;d++) acc[d] = e*vr[d];

        const bool b4 = (j & 16) != 0;
        float r8[8];
#pragma unroll
        for(int ii=0;ii<8;ii++){
            float snd  = b4 ? acc[ii]   : acc[ii+8];
            float kept = b4 ? acc[ii+8] : acc[ii];
            r8[ii] = kept + __shfl_xor(snd, 16);
        }
        const bool b3 = (j & 8) != 0;
        float r4[4];
#pragma unroll
        for(int ii=0;ii<4;ii++){
            float snd  = b3 ? r8[ii]   : r8[ii+4];
            float kept = b3 ? r8[ii+4] : r8[ii];
            r4[ii] = kept + __shfl_xor(snd, 8);
        }
        const bool b2 = (j & 4) != 0;
        float r2[2];
#pragma unroll
        for(int ii=0;ii<2;ii++){
            float snd  = b2 ? r4[ii]   : r4[ii+2];
            float kept = b2 ? r4[ii+2] : r4[ii];
            r2[ii] = kept + __shfl_xor(snd, 4);
        }
        const bool b1 = (j & 2) != 0;
        {
            float snd  = b1 ? r2[0] : r2[1];
            float kept = b1 ? r2[1] : r2[0];
            r2[0] = kept + __shfl_xor(snd, 2);
        }
        r2[0] += __shfl_xor(r2[0], 1);

        float inv = 1.0f/sum;
        if ((j&1)==0){
            int d = j>>1;
            int b_ = bh>>3, h = bh&7;
            msg0[(b_*N0+nq[it])*128 + h*16 + d] = m1d + r2[0]*inv;
        }
    }
}

// ---------------- output projection GEMM + bias (64-row tile) ----------------
__global__ __launch_bounds__(256) void k_out(const float* __restrict__ msg0, const float* __restrict__ Wo,
    const float* __restrict__ bo, float* __restrict__ out)
{
    __shared__ __align__(16) float At[16][68];
    __shared__ __align__(16) float Wt[16][132];
    const int t = threadIdx.x;
    const int m0 = blockIdx.x * 64;
    const int tx = t & 15, ty = t >> 4;

    float acc[4][8];
#pragma unroll
    for(int i=0;i<4;i++)
#pragma unroll
        for(int j=0;j<8;j++) acc[i][j]=0.f;

    const int ar = t>>2, akq = (t&3)*4;
    const int wo = t>>1, wkq = (t&1)*8;

    for(int kc=0;kc<128;kc+=16){
        float4 av = *(const float4*)(msg0 + (m0+ar)*128 + kc + akq);
        At[akq+0][ar] = av.x;
        At[akq+1][ar] = av.y;
        At[akq+2][ar] = av.z;
        At[akq+3][ar] = av.w;
        float4 w0 = *(const float4*)(Wo + wo*128 + kc + wkq);
        float4 w1 = *(const float4*)(Wo + wo*128 + kc + wkq + 4);
        Wt[wkq+0][wo] = w0.x; Wt[wkq+1][wo] = w0.y;
        Wt[wkq+2][wo] = w0.z; Wt[wkq+3][wo] = w0.w;
        Wt[wkq+4][wo] = w1.x; Wt[wkq+5][wo] = w1.y;
        Wt[wkq+6][wo] = w1.z; Wt[wkq+7][wo] = w1.w;
        __syncthreads();
#pragma unroll
        for(int kk=0;kk<16;kk++){
            float4 a4 = *(const float4*)&At[kk][ty*4];
            float4 wa = *(const float4*)&Wt[kk][tx*4];
            float4 wb = *(const float4*)&Wt[kk][64 + tx*4];
            float avr[4] = {a4.x,a4.y,a4.z,a4.w};
            float wvr[8] = {wa.x,wa.y,wa.z,wa.w, wb.x,wb.y,wb.z,wb.w};
#pragma unroll
            for(int i=0;i<4;i++)
#pragma unroll
                for(int j=0;j<8;j++) acc[i][j] += avr[i]*wvr[j];
        }
        __syncthreads();
    }
#pragma unroll
    for(int i=0;i<4;i++){
        int m = m0 + ty*4 + i;
        float4 sA = make_float4(acc[i][0]+bo[tx*4+0], acc[i][1]+bo[tx*4+1],
                                acc[i][2]+bo[tx*4+2], acc[i][3]+bo[tx*4+3]);
        float4 sB = make_float4(acc[i][4]+bo[64+tx*4+0], acc[i][5]+bo[64+tx*4+1],
                                acc[i][6]+bo[64+tx*4+2], acc[i][7]+bo[64+tx*4+3]);
        *(float4*)(out + m*128 + tx*4)      = sA;
        *(float4*)(out + m*128 + 64 + tx*4) = sB;
    }
}

extern "C" void kernel_launch(void* const* d_in, const int* in_sizes, int n_in,
                              void* d_out, int out_size, void* d_ws, size_t ws_size,
                              hipStream_t stream) {
    const float* x  = (const float*)d_in[0];
    const float* tg = (const float*)d_in[1];
    const float* Wq = (const float*)d_in[2];
    const float* Wk = (const float*)d_in[3];
    const float* Wv = (const float*)d_in[4];
    const float* Wo = (const float*)d_in[5];
    const float* bo = (const float*)d_in[6];

    float* ws = (float*)d_ws;
    float* q0   = ws + 0;
    float* k0   = ws + 2359296;
    float* v0   = ws + 4718592;
    float* q1   = ws + 7077888;
    float* k1   = ws + 7667712;
    float* v1   = ws + 8257536;
    float* q2   = ws + 8847360;
    float* k2   = ws + 8994816;   // k2T [bh][dg][m] float4
    float* v2   = ws + 9142272;   // v2T
    float* msg2 = ws + 9289728;
    float* msg0 = ws + 10027008;
    int*   idx2 = (int*)(ws + 12386304);

    k_proj<<<dim3(288,3), 256, 0, stream>>>(x, tg, Wq, Wk, Wv, q0, k0, v0);
    k_pool01<<<432, 256, 0, stream>>>((const float4*)q0, (float4*)q1,
                                      (float4*)q2, (float4*)k2, (float4*)v2);
    k_attn2<<<dim3(16,72), 256, 0, stream>>>(q2, k2, v2, msg2, idx2);
    k_ref10<<<9216, 256, 0, stream>>>(q1, k1, v1, q0, k0, v0, msg2, idx2, msg0);
    k_out<<<288, 256, 0, stream>>>(msg0, Wo, bo, (float*)d_out);
}

// Round 18
// 243.012 us; speedup vs baseline: 1.1760x; 1.1760x over previous
//
#include <hip/hip_runtime.h>

#define NB   2
#define NHD  8
#define BH   16
#define HD   16
#define N0   9216
#define N1   2304
#define N2   576
#define W0_  96
#define W1_  48
#define W2_  24
#define M_TOT 18432
#define TEMP 0.25f

// ---------------- projection GEMM (64-row tile): dst[(b,h,n,d)] = sum_c A[m][c]*W[o][c] ----------------
__global__ __launch_bounds__(256) void k_proj(const float* __restrict__ x, const float* __restrict__ tg,
    const float* __restrict__ Wq, const float* __restrict__ Wk, const float* __restrict__ Wv,
    float* __restrict__ q0, float* __restrict__ k0, float* __restrict__ v0)
{
    __shared__ __align__(16) float At[16][68];   // [k][row]
    __shared__ __align__(16) float Wt[16][132];  // [k][o]
    const int t = threadIdx.x;
    const int which = blockIdx.y;
    const float* A  = (which==0)? x : tg;
    const float* Wm = (which==0)? Wq : (which==1? Wk : Wv);
    float* dst      = (which==0)? q0 : (which==1? k0 : v0);
    const int m0 = blockIdx.x * 64;
    const int tx = t & 15, ty = t >> 4;

    float acc[4][8];
#pragma unroll
    for(int i=0;i<4;i++)
#pragma unroll
        for(int j=0;j<8;j++) acc[i][j]=0.f;

    const int ar = t>>2, akq = (t&3)*4;
    const int wo = t>>1, wkq = (t&1)*8;

    for(int kc=0;kc<128;kc+=16){
        float4 av = *(const float4*)(A + (m0+ar)*128 + kc + akq);
        At[akq+0][ar] = av.x;
        At[akq+1][ar] = av.y;
        At[akq+2][ar] = av.z;
        At[akq+3][ar] = av.w;
        float4 w0 = *(const float4*)(Wm + wo*128 + kc + wkq);
        float4 w1 = *(const float4*)(Wm + wo*128 + kc + wkq + 4);
        Wt[wkq+0][wo] = w0.x; Wt[wkq+1][wo] = w0.y;
        Wt[wkq+2][wo] = w0.z; Wt[wkq+3][wo] = w0.w;
        Wt[wkq+4][wo] = w1.x; Wt[wkq+5][wo] = w1.y;
        Wt[wkq+6][wo] = w1.z; Wt[wkq+7][wo] = w1.w;
        __syncthreads();
#pragma unroll
        for(int kk=0;kk<16;kk++){
            float4 a4 = *(const float4*)&At[kk][ty*4];
            float4 wa = *(const float4*)&Wt[kk][tx*4];
            float4 wb = *(const float4*)&Wt[kk][64 + tx*4];
            float avr[4] = {a4.x,a4.y,a4.z,a4.w};
            float wvr[8] = {wa.x,wa.y,wa.z,wa.w, wb.x,wb.y,wb.z,wb.w};
#pragma unroll
            for(int i=0;i<4;i++)
#pragma unroll
                for(int j=0;j<8;j++) acc[i][j] += avr[i]*wvr[j];
        }
        __syncthreads();
    }
    const int hA = tx>>2, dA = (tx&3)*4;
#pragma unroll
    for(int i=0;i<4;i++){
        int m = m0 + ty*4 + i;
        int b = m / N0; int n = m - b*N0;
        float4 sA = make_float4(acc[i][0], acc[i][1], acc[i][2], acc[i][3]);
        float4 sB = make_float4(acc[i][4], acc[i][5], acc[i][6], acc[i][7]);
        *(float4*)(dst + ((b*NHD + hA    )*N0 + n)*16 + dA) = sA;
        *(float4*)(dst + ((b*NHD + hA + 4)*N0 + n)*16 + dA) = sB;
    }
}

// ---- FUSED pooling: level0 -> level1 (row layout) AND level1 -> level2 (q row, k/v transposed) ----
__global__ __launch_bounds__(256) void k_pool01(const float4* __restrict__ src0,
    float4* __restrict__ dst1, float4* __restrict__ q2f,
    float4* __restrict__ k2T, float4* __restrict__ v2T)
{
    int tid = blockIdx.x*256 + threadIdx.x;
    if (tid >= 110592) return;
    int d4 = tid & 3;
    int rest = tid >> 2;
    int n2 = rest % N2; int g = rest / N2;     // g in [0,48): 0-15 q, 16-31 k, 32-47 v
    int yo2 = n2 / W2_, xo2 = n2 - yo2*W2_;

    const float4* s = src0 + g*N0*4;
    float4* d1 = dst1 + g*N1*4;
    float4 l1[4];
#pragma unroll
    for(int yy=0;yy<2;yy++){
#pragma unroll
        for(int xx=0;xx<2;xx++){
            int y1 = 2*yo2+yy, x1 = 2*xo2+xx;
            int n1 = y1*W1_ + x1;
            int cbase = (2*y1)*W0_ + 2*x1;
            float4 a = s[(cbase       )*4 + d4];
            float4 b = s[(cbase+1     )*4 + d4];
            float4 c = s[(cbase+W0_   )*4 + d4];
            float4 d = s[(cbase+W0_+1 )*4 + d4];
            float4 o;
            o.x = 0.25f*(a.x+b.x+c.x+d.x);
            o.y = 0.25f*(a.y+b.y+c.y+d.y);
            o.z = 0.25f*(a.z+b.z+c.z+d.z);
            o.w = 0.25f*(a.w+b.w+c.w+d.w);
            d1[n1*4 + d4] = o;
            l1[yy*2+xx] = o;
        }
    }
    float4 o2;
    o2.x = 0.25f*(l1[0].x+l1[1].x+l1[2].x+l1[3].x);
    o2.y = 0.25f*(l1[0].y+l1[1].y+l1[2].y+l1[3].y);
    o2.z = 0.25f*(l1[0].z+l1[1].z+l1[2].z+l1[3].z);
    o2.w = 0.25f*(l1[0].w+l1[1].w+l1[2].w+l1[3].w);
    int grp = g >> 4, bh = g & 15;
    if (grp == 0)      q2f[(bh*N2 + n2)*4 + d4] = o2;
    else if (grp == 1) k2T[(bh*4 + d4)*N2 + n2] = o2;
    else               v2T[(bh*4 + d4)*N2 + n2] = o2;
}

// ---- level-2 full attention + top-16: LDS-free, 1 query/wave, coalesced transposed k/v ----
__global__ __launch_bounds__(256) void k_attn2(const float* __restrict__ q2, const float* __restrict__ k2,
    const float* __restrict__ v2, float* __restrict__ msg2, int* __restrict__ idx2)
{
    const int bh = blockIdx.x;
    const int wv = threadIdx.x>>6, lane = threadIdx.x&63;
    const int q = blockIdx.y*4 + wv;   // one query per wave

    float qr[16];
    const float4* qp = (const float4*)(q2 + (bh*N2 + q)*16);
#pragma unroll
    for(int dq=0;dq<4;dq++){
        float4 va = qp[dq];
        qr[dq*4+0]=va.x; qr[dq*4+1]=va.y; qr[dq*4+2]=va.z; qr[dq*4+3]=va.w;
    }

    const float4* kT = (const float4*)k2 + bh*4*N2;   // [dg][m]
    const float4* vT = (const float4*)v2 + bh*4*N2;

    float ev[9];
    float mx = -1e30f;
#pragma unroll
    for(int t9=0;t9<9;t9++){
        int m = t9*64 + lane;
        float s = 0.f;
#pragma unroll
        for(int dg=0;dg<4;dg++){
            float4 kv = kT[dg*N2 + m];
            s += qr[dg*4+0]*kv.x;
            s += qr[dg*4+1]*kv.y;
            s += qr[dg*4+2]*kv.z;
            s += qr[dg*4+3]*kv.w;
        }
        s *= TEMP;
        ev[t9]=s;
        mx = fmaxf(mx, s);
    }
#pragma unroll
    for(int st=1; st<64; st<<=1) mx = fmaxf(mx, __shfl_xor(mx, st));

    float sum=0.f;
    float acc[16];
#pragma unroll
    for(int d=0;d<16;d++) acc[d]=0.f;
#pragma unroll
    for(int t9=0;t9<9;t9++){
        int m = t9*64 + lane;
        float e = expf(ev[t9]-mx);
        ev[t9]=e;
        sum += e;
#pragma unroll
        for(int dg=0;dg<4;dg++){
            float4 vv = vT[dg*N2 + m];
            acc[dg*4+0] += e*vv.x;
            acc[dg*4+1] += e*vv.y;
            acc[dg*4+2] += e*vv.z;
            acc[dg*4+3] += e*vv.w;
        }
    }
#pragma unroll
    for(int st=1; st<64; st<<=1) sum += __shfl_xor(sum, st);

    const bool b5 = (lane & 32) != 0;
    float r8[8];
#pragma unroll
    for(int i=0;i<8;i++){
        float snd  = b5 ? acc[i]   : acc[i+8];
        float kept = b5 ? acc[i+8] : acc[i];
        r8[i] = kept + __shfl_xor(snd, 32);
    }
    const bool b4 = (lane & 16) != 0;
    float r4[4];
#pragma unroll
    for(int i=0;i<4;i++){
        float snd  = b4 ? r8[i]   : r8[i+4];
        float kept = b4 ? r8[i+4] : r8[i];
        r4[i] = kept + __shfl_xor(snd, 16);
    }
    const bool b3 = (lane & 8) != 0;
    float r2[2];
#pragma unroll
    for(int i=0;i<2;i++){
        float snd  = b3 ? r4[i]   : r4[i+2];
        float kept = b3 ? r4[i+2] : r4[i];
        r2[i] = kept + __shfl_xor(snd, 8);
    }
    const bool b2 = (lane & 4) != 0;
    {
        float snd  = b2 ? r2[0] : r2[1];
        float kept = b2 ? r2[1] : r2[0];
        r2[0] = kept + __shfl_xor(snd, 4);
    }
    r2[0] += __shfl_xor(r2[0], 2);
    r2[0] += __shfl_xor(r2[0], 1);

    float inv = 1.0f/sum;
    if ((lane&3)==0){
        msg2[(bh*N2+q)*16 + (lane>>2)] = r2[0]*inv;
    }

    int id[9];
#pragma unroll
    for(int i=0;i<9;i++) id[i]=i;
#pragma unroll
    for(int p=0;p<8;p++){
#pragma unroll
        for(int i=0;i<8-p;i++){
            bool sw = (ev[i+1] > ev[i]) || (ev[i+1]==ev[i] && id[i+1]<id[i]);
            float tv = sw? ev[i+1]:ev[i]; float bv2 = sw? ev[i]:ev[i+1];
            int   ti = sw? id[i+1]:id[i]; int   bi  = sw? id[i]:id[i+1];
            ev[i]=tv; ev[i+1]=bv2; id[i]=ti; id[i+1]=bi;
        }
    }
    int* ip = idx2 + (bh*N2+q)*16;
    for(int it=0; it<16; it++){
        float bv = ev[0];
        int   bm = id[0]*64 + lane;
#pragma unroll
        for(int st=1; st<64; st<<=1){
            float ov = __shfl_xor(bv, st);
            int   om = __shfl_xor(bm, st);
            if (ov > bv || (ov==bv && om < bm)){ bv=ov; bm=om; }
        }
        if (lane==0) ip[it] = bm;
        if ((bm & 63) == lane){
#pragma unroll
            for(int i=0;i<8;i++){ ev[i]=ev[i+1]; id[i]=id[i+1]; }
            ev[8] = -1e30f;
        }
    }
}

// ---- FUSED refinement: wave owns 1 parent + its 4 children; shared candidate set, no barrier ----
__global__ __launch_bounds__(256) void k_ref10(
    const float* __restrict__ q1, const float* __restrict__ k1, const float* __restrict__ v1,
    const float* __restrict__ q0, const float* __restrict__ k0, const float* __restrict__ v0,
    const float* __restrict__ msg2, const int* __restrict__ idx2, float* __restrict__ msg0)
{
    __shared__ float msg1s[4][16];
    __shared__ int   idx1s[4][8];
    // XCD swizzle: 9216 blocks = 8 x 1152; each XCD owns 2 contiguous bh
    const int bid = (blockIdx.x & 7)*1152 + (blockIdx.x >> 3);
    const int bh = bid / 576, tile = bid - bh*576;
    const int tyy = tile / 24, txx = tile - tyy*24;
    const int py0 = tyy*2, px0 = txx*2;      // 2x2 parent tile origin (level-1 coords)
    const int wv = threadIdx.x>>6, lane = threadIdx.x&63;

    const int ppy = py0 + (wv>>1), ppx = px0 + (wv&1);   // this wave's parent (level-1)

    // ---------- phase 1: ref1 for parent wv ----------
    {
        const int n  = ppy*W1_ + ppx;
        const int par = (ppy>>1)*W2_ + (ppx>>1);
        const int kk = lane>>2, tt = lane&3, dy = tt>>1, dx = tt&1;
        int p = idx2[(bh*N2+par)*16 + kk];
        int ky = p / W2_, kx = p - ky*W2_;
        int child = (2*ky+dy)*W1_ + 2*kx+dx;

        const float* qp = q1 + (bh*N1+n)*16;
        float qr[16];
#pragma unroll
        for(int d=0; d<16; d+=4){
            float4 qq = *(const float4*)(qp+d);
            qr[d]=qq.x; qr[d+1]=qq.y; qr[d+2]=qq.z; qr[d+3]=qq.w;
        }
        const float4* kp = (const float4*)(k1 + (bh*N1+child)*16);
        float s = 0.f;
#pragma unroll
        for(int dq=0;dq<4;dq++){
            float4 kv = kp[dq];
            s += qr[dq*4+0]*kv.x + qr[dq*4+1]*kv.y + qr[dq*4+2]*kv.z + qr[dq*4+3]*kv.w;
        }
        s *= TEMP;
        float e = expf(s);
        float sum = e;
#pragma unroll
        for(int st=1; st<64; st<<=1) sum += __shfl_xor(sum, st);

        float acc[16];
        const float4* vp = (const float4*)(v1 + (bh*N1+child)*16);
#pragma unroll
        for(int dq=0;dq<4;dq++){
            float4 vv = vp[dq];
            acc[dq*4+0]=e*vv.x; acc[dq*4+1]=e*vv.y; acc[dq*4+2]=e*vv.z; acc[dq*4+3]=e*vv.w;
        }
        const bool b5 = (lane & 32) != 0;
        float r8[8];
#pragma unroll
        for(int ii=0;ii<8;ii++){
            float snd  = b5 ? acc[ii]   : acc[ii+8];
            float kept = b5 ? acc[ii+8] : acc[ii];
            r8[ii] = kept + __shfl_xor(snd, 32);
        }
        const bool b4 = (lane & 16) != 0;
        float r4[4];
#pragma unroll
        for(int ii=0;ii<4;ii++){
            float snd  = b4 ? r8[ii]   : r8[ii+4];
            float kept = b4 ? r8[ii+4] : r8[ii];
            r4[ii] = kept + __shfl_xor(snd, 16);
        }
        const bool b3 = (lane & 8) != 0;
        float r2[2];
#pragma unroll
        for(int ii=0;ii<2;ii++){
            float snd  = b3 ? r4[ii]   : r4[ii+2];
            float kept = b3 ? r4[ii+2] : r4[ii];
            r2[ii] = kept + __shfl_xor(snd, 8);
        }
        const bool b2 = (lane & 4) != 0;
        {
            float snd  = b2 ? r2[0] : r2[1];
            float kept = b2 ? r2[1] : r2[0];
            r2[0] = kept + __shfl_xor(snd, 4);
        }
        r2[0] += __shfl_xor(r2[0], 2);
        r2[0] += __shfl_xor(r2[0], 1);

        float inv1 = 1.0f/sum;
        if ((lane&3)==0){
            int d = lane>>2;
            msg1s[wv][d] = msg2[(bh*N2+par)*16 + d] + r2[0]*inv1;
        }
        int cnt = 0;
#pragma unroll
        for(int ii=0;ii<64;ii++){
            float si = __shfl(s, ii);
            if (si > s || (si == s && ii < lane)) cnt++;
        }
        if (cnt < 8) idx1s[wv][cnt] = child;
    }
    // no __syncthreads: each wave reads only its own msg1s[wv]/idx1s[wv] (in-wave DS order)

    // ---------- phase 2: this parent's 4 children; candidate set shared across both iterations ----------
    const int j = lane & 31, sub = lane >> 5;
    const int kk = j>>2, tt = j&3, dy = tt>>1, dx = tt&1;
    int p = idx1s[wv][kk];
    int ky = p / W1_, kx = p - ky*W1_;
    int child = (2*ky+dy)*W0_ + 2*kx+dx;

    float kr[16];
    {
        const float4* kp = (const float4*)(k0 + (bh*N0+child)*16);
#pragma unroll
        for(int dq=0;dq<4;dq++){
            float4 kv = kp[dq];
            kr[dq*4+0]=kv.x; kr[dq*4+1]=kv.y; kr[dq*4+2]=kv.z; kr[dq*4+3]=kv.w;
        }
    }
    const int cy0 = 2*ppy, cx0 = 2*ppx + sub;
    int nq[2];
    float s_[2];
#pragma unroll
    for(int it=0; it<2; it++){
        nq[it] = (cy0+it)*W0_ + cx0;
        const float* qp = q0 + (bh*N0+nq[it])*16;
        float qr[16];
#pragma unroll
        for(int d=0; d<16; d+=4){
            float4 qq = *(const float4*)(qp+d);
            qr[d]=qq.x; qr[d+1]=qq.y; qr[d+2]=qq.z; qr[d+3]=qq.w;
        }
        float s = 0.f;
#pragma unroll
        for(int dq=0;dq<4;dq++){
            s += qr[dq*4+0]*kr[dq*4+0] + qr[dq*4+1]*kr[dq*4+1]
               + qr[dq*4+2]*kr[dq*4+2] + qr[dq*4+3]*kr[dq*4+3];
        }
        s_[it] = s * TEMP;
    }
    float vr[16];
    {
        const float4* vp = (const float4*)(v0 + (bh*N0+child)*16);
#pragma unroll
        for(int dq=0;dq<4;dq++){
            float4 vv = vp[dq];
            vr[dq*4+0]=vv.x; vr[dq*4+1]=vv.y; vr[dq*4+2]=vv.z; vr[dq*4+3]=vv.w;
        }
    }
    const float m1d = msg1s[wv][j>>1];

#pragma unroll
    for(int it=0; it<2; it++){
        float e = expf(s_[it]);
        float sum = e;
#pragma unroll
        for(int st=1; st<32; st<<=1) sum += __shfl_xor(sum, st);

        float acc[16];
#pragma unroll
        for(int d=0;d<16;d++) acc[d] = e*vr[d];

        const bool b4 = (j & 16) != 0;
        float r8[8];
#pragma unroll
        for(int ii=0;ii<8;ii++){
            float snd  = b4 ? acc[ii]   : acc[ii+8];
            float kept = b4 ? acc[ii+8] : acc[ii];
            r8[ii] = kept + __shfl_xor(snd, 16);
        }
        const bool b3 = (j & 8) != 0;
        float r4[4];
#pragma unroll
        for(int ii=0;ii<4;ii++){
            float snd  = b3 ? r8[ii]   : r8[ii+4];
            float kept = b3 ? r8[ii+4] : r8[ii];
            r4[ii] = kept + __shfl_xor(snd, 8);
        }
        const bool b2 = (j & 4) != 0;
        float r2[2];
#pragma unroll
        for(int ii=0;ii<2;ii++){
            float snd  = b2 ? r4[ii]   : r4[ii+2];
            float kept = b2 ? r4[ii+2] : r4[ii];
            r2[ii] = kept + __shfl_xor(snd, 4);
        }
        const bool b1 = (j & 2) != 0;
        {
            float snd  = b1 ? r2[0] : r2[1];
            float kept = b1 ? r2[1] : r2[0];
            r2[0] = kept + __shfl_xor(snd, 2);
        }
        r2[0] += __shfl_xor(r2[0], 1);

        float inv = 1.0f/sum;
        if ((j&1)==0){
            int d = j>>1;
            int b_ = bh>>3, h = bh&7;
            msg0[(b_*N0+nq[it])*128 + h*16 + d] = m1d + r2[0]*inv;
        }
    }
}

// ---------------- output projection GEMM + bias (64-row tile) ----------------
__global__ __launch_bounds__(256) void k_out(const float* __restrict__ msg0, const float* __restrict__ Wo,
    const float* __restrict__ bo, float* __restrict__ out)
{
    __shared__ __align__(16) float At[16][68];
    __shared__ __align__(16) float Wt[16][132];
    const int t = threadIdx.x;
    const int m0 = blockIdx.x * 64;
    const int tx = t & 15, ty = t >> 4;

    float acc[4][8];
#pragma unroll
    for(int i=0;i<4;i++)
#pragma unroll
        for(int j=0;j<8;j++) acc[i][j]=0.f;

    const int ar = t>>2, akq = (t&3)*4;
    const int wo = t>>1, wkq = (t&1)*8;

    for(int kc=0;kc<128;kc+=16){
        float4 av = *(const float4*)(msg0 + (m0+ar)*128 + kc + akq);
        At[akq+0][ar] = av.x;
        At[akq+1][ar] = av.y;
        At[akq+2][ar] = av.z;
        At[akq+3][ar] = av.w;
        float4 w0 = *(const float4*)(Wo + wo*128 + kc + wkq);
        float4 w1 = *(const float4*)(Wo + wo*128 + kc + wkq + 4);
        Wt[wkq+0][wo] = w0.x; Wt[wkq+1][wo] = w0.y;
        Wt[wkq+2][wo] = w0.z; Wt[wkq+3][wo] = w0.w;
        Wt[wkq+4][wo] = w1.x; Wt[wkq+5][wo] = w1.y;
        Wt[wkq+6][wo] = w1.z; Wt[wkq+7][wo] = w1.w;
        __syncthreads();
#pragma unroll
        for(int kk=0;kk<16;kk++){
            float4 a4 = *(const float4*)&At[kk][ty*4];
            float4 wa = *(const float4*)&Wt[kk][tx*4];
            float4 wb = *(const float4*)&Wt[kk][64 + tx*4];
            float avr[4] = {a4.x,a4.y,a4.z,a4.w};
            float wvr[8] = {wa.x,wa.y,wa.z,wa.w, wb.x,wb.y,wb.z,wb.w};
#pragma unroll
            for(int i=0;i<4;i++)
#pragma unroll
                for(int j=0;j<8;j++) acc[i][j] += avr[i]*wvr[j];
        }
        __syncthreads();
    }
#pragma unroll
    for(int i=0;i<4;i++){
        int m = m0 + ty*4 + i;
        float4 sA = make_float4(acc[i][0]+bo[tx*4+0], acc[i][1]+bo[tx*4+1],
                                acc[i][2]+bo[tx*4+2], acc[i][3]+bo[tx*4+3]);
        float4 sB = make_float4(acc[i][4]+bo[64+tx*4+0], acc[i][5]+bo[64+tx*4+1],
                                acc[i][6]+bo[64+tx*4+2], acc[i][7]+bo[64+tx*4+3]);
        *(float4*)(out + m*128 + tx*4)      = sA;
        *(float4*)(out + m*128 + 64 + tx*4) = sB;
    }
}

extern "C" void kernel_launch(void* const* d_in, const int* in_sizes, int n_in,
                              void* d_out, int out_size, void* d_ws, size_t ws_size,
                              hipStream_t stream) {
    const float* x  = (const float*)d_in[0];
    const float* tg = (const float*)d_in[1];
    const float* Wq = (const float*)d_in[2];
    const float* Wk = (const float*)d_in[3];
    const float* Wv = (const float*)d_in[4];
    const float* Wo = (const float*)d_in[5];
    const float* bo = (const float*)d_in[6];

    float* ws = (float*)d_ws;
    float* q0   = ws + 0;
    float* k0   = ws + 2359296;
    float* v0   = ws + 4718592;
    float* q1   = ws + 7077888;
    float* k1   = ws + 7667712;
    float* v1   = ws + 8257536;
    float* q2   = ws + 8847360;
    float* k2   = ws + 8994816;   // k2T [bh][dg][m] float4
    float* v2   = ws + 9142272;   // v2T
    float* msg2 = ws + 9289728;
    float* msg0 = ws + 10027008;
    int*   idx2 = (int*)(ws + 12386304);

    k_proj<<<dim3(288,3), 256, 0, stream>>>(x, tg, Wq, Wk, Wv, q0, k0, v0);
    k_pool01<<<432, 256, 0, stream>>>((const float4*)q0, (float4*)q1,
                                      (float4*)q2, (float4*)k2, (float4*)v2);
    k_attn2<<<dim3(16,144), 256, 0, stream>>>(q2, k2, v2, msg2, idx2);
    k_ref10<<<9216, 256, 0, stream>>>(q1, k1, v1, q0, k0, v0, msg2, idx2, msg0);
    k_out<<<288, 256, 0, stream>>>(msg0, Wo, bo, (float*)d_out);
}